// Round 1
// baseline (676.099 us; speedup 1.0000x reference)
//
#include <hip/hip_runtime.h>
#include <hip/hip_bf16.h>
#include <stdint.h>

typedef unsigned long long u64;
typedef unsigned int u32;

#define NANCH 10647
#define NBATCH 16
#define NSORT 16384
#define NSEL 2048
#define NWORD 32
#define CONF_T 0.5f
#define NMS_T 0.5f
#define MAXDET 300
#define MAXWH 4096.0f

// ---------------- Kernel 1: per-anchor prep ----------------
__global__ __launch_bounds__(256) void k_prep(const float* __restrict__ pred,
                                              u64* __restrict__ keys,
                                              float4* __restrict__ boxes,
                                              int* __restrict__ cls,
                                              float* __restrict__ score) {
    __shared__ float sm[128 * 85];
    int b = blockIdx.y;
    int a0 = blockIdx.x * 128;
    int na = NANCH - a0; if (na > 128) na = 128;
    const float* src = pred + ((size_t)b * NANCH + a0) * 85;
    int tot = na * 85;
    for (int i = threadIdx.x; i < tot; i += 256) sm[i] = src[i];
    __syncthreads();
    int t = threadIdx.x;
    if (t < na) {
        const float* s = &sm[t * 85];
        float x = s[0], y = s[1], w = s[2], h = s[3], obj = s[4];
        float best = s[5] * obj; int arg = 0;
        #pragma unroll
        for (int c = 1; c < 80; ++c) {
            float v = s[5 + c] * obj;
            if (v > best) { best = v; arg = c; }
        }
        bool valid = obj >= CONF_T;
        float sc = valid ? best : -1.0f;
        int a = a0 + t;
        float4 bx;
        bx.x = x - w * 0.5f; bx.y = y - h * 0.5f;
        bx.z = x + w * 0.5f; bx.w = y + h * 0.5f;
        size_t o = (size_t)b * NANCH + a;
        boxes[o] = bx;
        cls[o] = arg;
        score[o] = sc;
        u32 u = __float_as_uint(sc);
        u32 v = (u & 0x80000000u) ? ~u : (u | 0x80000000u); // ascending map
        u32 hi = ~v;                                        // descending
        keys[(size_t)b * NSORT + a] = ((u64)hi << 32) | (u32)a;
    }
}

// ---------------- Kernel 2: bitonic sort + gather top-2048 ----------------
__global__ __launch_bounds__(1024) void k_sort(const u64* __restrict__ keys,
                                               const float4* __restrict__ boxes,
                                               const int* __restrict__ cls,
                                               const float* __restrict__ score,
                                               float4* __restrict__ sel_box,
                                               float4* __restrict__ sel_sbox,
                                               float* __restrict__ sel_area,
                                               float* __restrict__ sel_score,
                                               int* __restrict__ sel_cls) {
    __shared__ u64 sk[NSORT];   // 128 KB
    int b = blockIdx.x;
    for (int i = threadIdx.x; i < NSORT; i += 1024)
        sk[i] = (i < NANCH) ? keys[(size_t)b * NSORT + i] : ~0ULL;
    __syncthreads();
    for (int k = 2; k <= NSORT; k <<= 1) {
        for (int j = k >> 1; j > 0; j >>= 1) {
            for (int n = threadIdx.x; n < NSORT / 2; n += 1024) {
                int i = ((n & ~(j - 1)) << 1) | (n & (j - 1));
                int l = i | j;
                u64 a = sk[i], c = sk[l];
                bool up = ((i & k) == 0);
                if ((a > c) == up) { sk[i] = c; sk[l] = a; }
            }
            __syncthreads();
        }
    }
    for (int r = threadIdx.x; r < NSEL; r += 1024) {
        u64 key = sk[r];
        int a = (int)(key & 0xFFFFFFFFu);
        size_t src = (size_t)b * NANCH + a;
        float4 bx = boxes[src];
        int c = cls[src];
        float sc = score[src];
        float off = (float)c * MAXWH;
        float4 sb;
        sb.x = bx.x + off; sb.y = bx.y + off;
        sb.z = bx.z + off; sb.w = bx.w + off;
        float area = (sb.z - sb.x) * (sb.w - sb.y);
        size_t o = (size_t)b * NSEL + r;
        sel_box[o] = bx; sel_sbox[o] = sb; sel_area[o] = area;
        sel_score[o] = sc; sel_cls[o] = c;
    }
}

// ---------------- Kernel 3: IoU predicate bitmask rows ----------------
__global__ __launch_bounds__(256) void k_iou(const float4* __restrict__ sel_sbox,
                                             const float* __restrict__ sel_area,
                                             u64* __restrict__ rowmask) {
    int b = blockIdx.y;
    int i = blockIdx.x;
    const float4* SB = sel_sbox + (size_t)b * NSEL;
    const float* AR = sel_area + (size_t)b * NSEL;
    float4 bi = SB[i];
    float ai = AR[i];
    int lane = threadIdx.x & 63;
    int wv = threadIdx.x >> 6;
    #pragma unroll
    for (int kk = 0; kk < 8; ++kk) {
        int chunk = wv * 8 + kk;
        int j = chunk * 64 + lane;
        float4 bj = SB[j];
        float aj = AR[j];
        float ltx = fmaxf(bi.x, bj.x), lty = fmaxf(bi.y, bj.y);
        float rbx = fminf(bi.z, bj.z), rby = fminf(bi.w, bj.w);
        float w = fmaxf(rbx - ltx, 0.0f), h = fmaxf(rby - lty, 0.0f);
        float inter = w * h;
        float iou = inter / (ai + aj - inter + 1e-16f);
        u64 m = __ballot(iou > NMS_T);
        if (lane == 0) rowmask[((size_t)b * NSEL + i) * NWORD + chunk] = m;
    }
}

// ---------------- Kernel 4: sequential NMS scan + output ----------------
__global__ __launch_bounds__(64) void k_nms(const u64* __restrict__ rowmask,
                                            const float4* __restrict__ sel_box,
                                            const float* __restrict__ sel_score,
                                            const int* __restrict__ sel_cls,
                                            float* __restrict__ out) {
    __shared__ u64 srow[128 * NWORD];   // 32 KB
    int b = blockIdx.x;
    int lane = threadIdx.x;
    const u64* RM = rowmask + (size_t)b * NSEL * NWORD;
    const float* SC = sel_score + (size_t)b * NSEL;

    // valid bit words: lane w holds word w (w<32)
    u64 vw = 0;
    for (int w = 0; w < NWORD; ++w) {
        bool p = SC[w * 64 + lane] >= 0.0f;
        u64 m = __ballot(p);
        if (lane == w) vw = m;
    }

    u64 kw = 0;   // keep word for this lane (lane < 32)
    for (int c0 = 0; c0 < NSEL; c0 += 128) {
        for (int idx = lane; idx < 128 * NWORD; idx += 64)
            srow[idx] = RM[(size_t)c0 * NWORD + idx];
        __syncthreads();
        #pragma unroll 4
        for (int r = 0; r < 128; ++r) {
            int i = c0 + r;
            u64 w = (lane < NWORD) ? srow[r * NWORD + lane] : 0ULL;
            bool hit = (kw & w) != 0ULL;
            u64 anyhit = __ballot(hit);
            int wi = i >> 6, bi2 = i & 63;
            u64 vword = __shfl(vw, wi);
            bool keep_i = (anyhit == 0ULL) && ((vword >> bi2) & 1ULL);
            if (lane == wi && keep_i) kw |= (1ULL << bi2);
        }
        __syncthreads();
    }

    // compact kept entries (already in descending-score order) into out
    int cnt = (lane < NWORD) ? __popcll(kw) : 0;
    int pre = cnt;
    #pragma unroll
    for (int d = 1; d < 64; d <<= 1) {
        int o = __shfl_up(pre, d);
        if (lane >= d) pre += o;
    }
    int total = __shfl(pre, 63);
    int base = pre - cnt;
    float* OUT = out + (size_t)b * MAXDET * 6;
    if (lane < NWORD) {
        u64 m = kw;
        int r = 0;
        while (m) {
            int t = __ffsll((long long)m) - 1;
            m &= m - 1;
            int slot = base + r; ++r;
            if (slot < MAXDET) {
                int i = lane * 64 + t;
                size_t src = (size_t)b * NSEL + i;
                float4 bx = sel_box[src];
                float sc = SC[i];
                int c = sel_cls[src];
                float* o6 = OUT + slot * 6;
                o6[0] = bx.x; o6[1] = bx.y; o6[2] = bx.z; o6[3] = bx.w;
                o6[4] = sc; o6[5] = (float)c;
            }
        }
    }
    int start = total > MAXDET ? MAXDET : total;
    for (int s = start + lane; s < MAXDET; s += 64) {
        float* o6 = OUT + s * 6;
        o6[0] = 0.0f; o6[1] = 0.0f; o6[2] = 0.0f;
        o6[3] = 0.0f; o6[4] = 0.0f; o6[5] = 0.0f;
    }
}

// ---------------- Launcher ----------------
extern "C" void kernel_launch(void* const* d_in, const int* in_sizes, int n_in,
                              void* d_out, int out_size, void* d_ws, size_t ws_size,
                              hipStream_t stream) {
    const float* pred = (const float*)d_in[0];
    float* out = (float*)d_out;

    char* ws = (char*)d_ws;
    size_t off = 0;
    auto alloc = [&](size_t bytes) -> void* {
        void* p = ws + off;
        off += (bytes + 255) & ~(size_t)255;
        return p;
    };

    u64*    keys      = (u64*)   alloc((size_t)NBATCH * NSORT * 8);
    float4* boxes     = (float4*)alloc((size_t)NBATCH * NANCH * 16);
    int*    cls       = (int*)   alloc((size_t)NBATCH * NANCH * 4);
    float*  score     = (float*) alloc((size_t)NBATCH * NANCH * 4);
    float4* sel_box   = (float4*)alloc((size_t)NBATCH * NSEL * 16);
    float4* sel_sbox  = (float4*)alloc((size_t)NBATCH * NSEL * 16);
    float*  sel_area  = (float*) alloc((size_t)NBATCH * NSEL * 4);
    float*  sel_score = (float*) alloc((size_t)NBATCH * NSEL * 4);
    int*    sel_cls   = (int*)   alloc((size_t)NBATCH * NSEL * 4);
    u64*    rowmask   = (u64*)   alloc((size_t)NBATCH * NSEL * NWORD * 8);

    dim3 g1((NANCH + 127) / 128, NBATCH);
    k_prep<<<g1, 256, 0, stream>>>(pred, keys, boxes, cls, score);

    k_sort<<<NBATCH, 1024, 0, stream>>>(keys, boxes, cls, score,
                                        sel_box, sel_sbox, sel_area,
                                        sel_score, sel_cls);

    dim3 g3(NSEL, NBATCH);
    k_iou<<<g3, 256, 0, stream>>>(sel_sbox, sel_area, rowmask);

    k_nms<<<NBATCH, 64, 0, stream>>>(rowmask, sel_box, sel_score, sel_cls, out);
}

// Round 2
// 390.134 us; speedup vs baseline: 1.7330x; 1.7330x over previous
//
#include <hip/hip_runtime.h>
#include <hip/hip_bf16.h>
#include <stdint.h>

typedef unsigned long long u64;
typedef unsigned int u32;

#define NANCH 10647
#define NBATCH 16
#define NSORT 16384
#define NSEL 2048
#define NWORD 32
#define CONF_T 0.5f
#define NMS_T 0.5f
#define MAXDET 300
#define MAXWH 4096.0f

// ---------------- Kernel 1: per-anchor prep ----------------
__global__ __launch_bounds__(256) void k_prep(const float* __restrict__ pred,
                                              u64* __restrict__ keys,
                                              float4* __restrict__ boxes,
                                              int* __restrict__ cls,
                                              float* __restrict__ score) {
    __shared__ float sm[128 * 85];
    int b = blockIdx.y;
    int a0 = blockIdx.x * 128;
    int na = NANCH - a0; if (na > 128) na = 128;
    const float* src = pred + ((size_t)b * NANCH + a0) * 85;
    int tot = na * 85;
    for (int i = threadIdx.x; i < tot; i += 256) sm[i] = src[i];
    __syncthreads();
    int t = threadIdx.x;
    if (t < na) {
        const float* s = &sm[t * 85];
        float x = s[0], y = s[1], w = s[2], h = s[3], obj = s[4];
        float best = s[5] * obj; int arg = 0;
        #pragma unroll
        for (int c = 1; c < 80; ++c) {
            float v = s[5 + c] * obj;
            if (v > best) { best = v; arg = c; }
        }
        bool valid = obj >= CONF_T;
        float sc = valid ? best : -1.0f;
        int a = a0 + t;
        float4 bx;
        bx.x = x - w * 0.5f; bx.y = y - h * 0.5f;
        bx.z = x + w * 0.5f; bx.w = y + h * 0.5f;
        size_t o = (size_t)b * NANCH + a;
        boxes[o] = bx;
        cls[o] = arg;
        score[o] = sc;
        u32 u = __float_as_uint(sc);
        u32 v = (u & 0x80000000u) ? ~u : (u | 0x80000000u); // ascending map
        u32 hi = ~v;                                        // descending
        keys[(size_t)b * NSORT + a] = ((u64)hi << 32) | (u32)a;
    }
}

// ---------------- Kernel 2: bitonic sort + gather top-2048 ----------------
__global__ __launch_bounds__(1024) void k_sort(const u64* __restrict__ keys,
                                               const float4* __restrict__ boxes,
                                               const int* __restrict__ cls,
                                               const float* __restrict__ score,
                                               float4* __restrict__ sel_box,
                                               float4* __restrict__ sel_sbox,
                                               float* __restrict__ sel_area,
                                               float* __restrict__ sel_score,
                                               int* __restrict__ sel_cls) {
    __shared__ u64 sk[NSORT];   // 128 KB
    int b = blockIdx.x;
    for (int i = threadIdx.x; i < NSORT; i += 1024)
        sk[i] = (i < NANCH) ? keys[(size_t)b * NSORT + i] : ~0ULL;
    __syncthreads();
    for (int k = 2; k <= NSORT; k <<= 1) {
        for (int j = k >> 1; j > 0; j >>= 1) {
            for (int n = threadIdx.x; n < NSORT / 2; n += 1024) {
                int i = ((n & ~(j - 1)) << 1) | (n & (j - 1));
                int l = i | j;
                u64 a = sk[i], c = sk[l];
                bool up = ((i & k) == 0);
                if ((a > c) == up) { sk[i] = c; sk[l] = a; }
            }
            __syncthreads();
        }
    }
    for (int r = threadIdx.x; r < NSEL; r += 1024) {
        u64 key = sk[r];
        int a = (int)(key & 0xFFFFFFFFu);
        size_t src = (size_t)b * NANCH + a;
        float4 bx = boxes[src];
        int c = cls[src];
        float sc = score[src];
        float off = (float)c * MAXWH;
        float4 sb;
        sb.x = bx.x + off; sb.y = bx.y + off;
        sb.z = bx.z + off; sb.w = bx.w + off;
        float area = (sb.z - sb.x) * (sb.w - sb.y);
        size_t o = (size_t)b * NSEL + r;
        sel_box[o] = bx; sel_sbox[o] = sb; sel_area[o] = area;
        sel_score[o] = sc; sel_cls[o] = c;
    }
}

// ---------------- Kernel 3: IoU predicate bitmask rows ----------------
__global__ __launch_bounds__(256) void k_iou(const float4* __restrict__ sel_sbox,
                                             const float* __restrict__ sel_area,
                                             u64* __restrict__ rowmask) {
    int b = blockIdx.y;
    int i = blockIdx.x;
    const float4* SB = sel_sbox + (size_t)b * NSEL;
    const float* AR = sel_area + (size_t)b * NSEL;
    float4 bi = SB[i];
    float ai = AR[i];
    int lane = threadIdx.x & 63;
    int wv = threadIdx.x >> 6;
    #pragma unroll
    for (int kk = 0; kk < 8; ++kk) {
        int chunk = wv * 8 + kk;
        int j = chunk * 64 + lane;
        float4 bj = SB[j];
        float aj = AR[j];
        float ltx = fmaxf(bi.x, bj.x), lty = fmaxf(bi.y, bj.y);
        float rbx = fminf(bi.z, bj.z), rby = fminf(bi.w, bj.w);
        float w = fmaxf(rbx - ltx, 0.0f), h = fmaxf(rby - lty, 0.0f);
        float inter = w * h;
        float iou = inter / (ai + aj - inter + 1e-16f);
        u64 m = __ballot(iou > NMS_T);
        if (lane == 0) rowmask[((size_t)b * NSEL + i) * NWORD + chunk] = m;
    }
}

// ---------------- Kernel 4: chunked NMS scan + output ----------------
__global__ __launch_bounds__(64) void k_nms(const u64* __restrict__ rowmask,
                                            const float4* __restrict__ sel_box,
                                            const float* __restrict__ sel_score,
                                            const int* __restrict__ sel_cls,
                                            float* __restrict__ out) {
    int b = blockIdx.x;
    int lane = threadIdx.x;
    const u64* RM = rowmask + (size_t)b * NSEL * NWORD;
    const float* SC = sel_score + (size_t)b * NSEL;

    // vreg: lane w holds valid word w (w < 32)
    u64 vreg = 0;
    for (int w = 0; w < NWORD; ++w) {
        bool p = SC[w * 64 + lane] >= 0.0f;
        u64 m = __ballot(p);
        if (lane == w) vreg = m;
    }

    u64 kreg = 0;   // lane c holds keep word of chunk c (c < 32)
    for (int d = 0; d < NWORD; ++d) {
        int row = d * 64 + lane;               // this lane's candidate in chunk d
        const u64* rp = RM + (size_t)row * NWORD;

        // cross-chunk suppression: any previously-kept j with iou > T?
        bool hit = false;
        #pragma unroll 8
        for (int c = 0; c < d; ++c) {
            u64 kc = __shfl(kreg, c);
            u64 rm = rp[c];
            hit = hit | ((rm & kc) != 0ULL);
        }
        u64 diag = rp[d];                      // intra-chunk suppressor bits
        u64 hitword = __ballot(hit);
        u64 vword = __shfl(vreg, d);
        u64 pend = vword & ~hitword;           // candidates still eligible

        // intra-chunk triangular resolution (all lanes compute identical k)
        u64 k = 0;
        #pragma unroll
        for (int t = 0; t < 64; ++t) {
            u64 rowt = __shfl(diag, t);        // independent of k -> pipelined
            bool kt = (((pend >> t) & 1ULL) != 0ULL) & ((rowt & k) == 0ULL);
            k |= ((u64)kt) << t;
        }
        if (lane == d) kreg = k;
    }

    // compact kept entries (already in descending-score order) into out
    int cnt = (lane < NWORD) ? __popcll(kreg) : 0;
    int pre = cnt;
    #pragma unroll
    for (int dd = 1; dd < 64; dd <<= 1) {
        int o = __shfl_up(pre, dd);
        if (lane >= dd) pre += o;
    }
    int total = __shfl(pre, 63);
    int base = pre - cnt;
    float* OUT = out + (size_t)b * MAXDET * 6;
    if (lane < NWORD) {
        u64 m = kreg;
        int r = 0;
        while (m) {
            int t = __ffsll((long long)m) - 1;
            m &= m - 1;
            int slot = base + r; ++r;
            if (slot < MAXDET) {
                int i = lane * 64 + t;
                size_t src = (size_t)b * NSEL + i;
                float4 bx = sel_box[src];
                float sc = SC[i];
                int c = sel_cls[src];
                float* o6 = OUT + slot * 6;
                o6[0] = bx.x; o6[1] = bx.y; o6[2] = bx.z; o6[3] = bx.w;
                o6[4] = sc; o6[5] = (float)c;
            }
        }
    }
    int start = total > MAXDET ? MAXDET : total;
    for (int s = start + lane; s < MAXDET; s += 64) {
        float* o6 = OUT + s * 6;
        o6[0] = 0.0f; o6[1] = 0.0f; o6[2] = 0.0f;
        o6[3] = 0.0f; o6[4] = 0.0f; o6[5] = 0.0f;
    }
}

// ---------------- Launcher ----------------
extern "C" void kernel_launch(void* const* d_in, const int* in_sizes, int n_in,
                              void* d_out, int out_size, void* d_ws, size_t ws_size,
                              hipStream_t stream) {
    const float* pred = (const float*)d_in[0];
    float* out = (float*)d_out;

    char* ws = (char*)d_ws;
    size_t off = 0;
    auto alloc = [&](size_t bytes) -> void* {
        void* p = ws + off;
        off += (bytes + 255) & ~(size_t)255;
        return p;
    };

    u64*    keys      = (u64*)   alloc((size_t)NBATCH * NSORT * 8);
    float4* boxes     = (float4*)alloc((size_t)NBATCH * NANCH * 16);
    int*    cls       = (int*)   alloc((size_t)NBATCH * NANCH * 4);
    float*  score     = (float*) alloc((size_t)NBATCH * NANCH * 4);
    float4* sel_box   = (float4*)alloc((size_t)NBATCH * NSEL * 16);
    float4* sel_sbox  = (float4*)alloc((size_t)NBATCH * NSEL * 16);
    float*  sel_area  = (float*) alloc((size_t)NBATCH * NSEL * 4);
    float*  sel_score = (float*) alloc((size_t)NBATCH * NSEL * 4);
    int*    sel_cls   = (int*)   alloc((size_t)NBATCH * NSEL * 4);
    u64*    rowmask   = (u64*)   alloc((size_t)NBATCH * NSEL * NWORD * 8);

    dim3 g1((NANCH + 127) / 128, NBATCH);
    k_prep<<<g1, 256, 0, stream>>>(pred, keys, boxes, cls, score);

    k_sort<<<NBATCH, 1024, 0, stream>>>(keys, boxes, cls, score,
                                        sel_box, sel_sbox, sel_area,
                                        sel_score, sel_cls);

    dim3 g3(NSEL, NBATCH);
    k_iou<<<g3, 256, 0, stream>>>(sel_sbox, sel_area, rowmask);

    k_nms<<<NBATCH, 64, 0, stream>>>(rowmask, sel_box, sel_score, sel_cls, out);
}

// Round 3
// 282.336 us; speedup vs baseline: 2.3947x; 1.3818x over previous
//
#include <hip/hip_runtime.h>
#include <hip/hip_bf16.h>
#include <stdint.h>

typedef unsigned long long u64;
typedef unsigned int u32;

#define NANCH 10647
#define NBATCH 16
#define NSORT 16384
#define NSEL 2048
#define NWORD 32
#define CONF_T 0.5f
#define NMS_T 0.5f
#define MAXDET 300
#define MAXWH 4096.0f

// ---------------- Kernel 1: per-anchor prep ----------------
__global__ __launch_bounds__(256) void k_prep(const float* __restrict__ pred,
                                              u64* __restrict__ keys,
                                              float4* __restrict__ boxes,
                                              int* __restrict__ cls,
                                              float* __restrict__ score) {
    __shared__ float sm[128 * 85];
    int b = blockIdx.y;
    int a0 = blockIdx.x * 128;
    int na = NANCH - a0; if (na > 128) na = 128;
    const float* src = pred + ((size_t)b * NANCH + a0) * 85;
    int tot = na * 85;
    for (int i = threadIdx.x; i < tot; i += 256) sm[i] = src[i];
    __syncthreads();
    int t = threadIdx.x;
    if (t < na) {
        const float* s = &sm[t * 85];
        float x = s[0], y = s[1], w = s[2], h = s[3], obj = s[4];
        float best = s[5] * obj; int arg = 0;
        #pragma unroll
        for (int c = 1; c < 80; ++c) {
            float v = s[5 + c] * obj;
            if (v > best) { best = v; arg = c; }
        }
        bool valid = obj >= CONF_T;
        float sc = valid ? best : -1.0f;
        int a = a0 + t;
        float4 bx;
        bx.x = x - w * 0.5f; bx.y = y - h * 0.5f;
        bx.z = x + w * 0.5f; bx.w = y + h * 0.5f;
        size_t o = (size_t)b * NANCH + a;
        boxes[o] = bx;
        cls[o] = arg;
        score[o] = sc;
        u32 u = __float_as_uint(sc);
        u32 v = (u & 0x80000000u) ? ~u : (u | 0x80000000u); // ascending map
        u32 hi = ~v;                                        // descending
        keys[(size_t)b * NSORT + a] = ((u64)hi << 32) | (u32)a;
    }
}

// ------- Kernel 2: radix-select top-2048 + bitonic sort + gather -------
__global__ __launch_bounds__(1024) void k_sel(const u64* __restrict__ keys,
                                              const float4* __restrict__ boxes,
                                              const int* __restrict__ cls,
                                              const float* __restrict__ score,
                                              float4* __restrict__ sel_box,
                                              float4* __restrict__ sel_sbox,
                                              float* __restrict__ sel_area,
                                              float* __restrict__ sel_score,
                                              int* __restrict__ sel_cls) {
    __shared__ u64 sk[NSEL];        // 16 KB
    __shared__ u32 hist[256];
    __shared__ u32 hsc[256];
    __shared__ u64 s_P;             // known-prefix value
    __shared__ u64 s_M;             // known-prefix mask
    __shared__ u32 s_rank;
    __shared__ u32 s_cnt;

    int b = blockIdx.x;
    int tid = threadIdx.x;
    const u64* KB = keys + (size_t)b * NSORT;

    if (tid == 0) { s_P = 0; s_M = 0; s_rank = NSEL; s_cnt = 0; }
    __syncthreads();

    // ---- Phase A: radix-select the 2048th-smallest key ----
    // key bits [31:14] are always zero (index < 16384), so 6 digit rounds
    const int shifts[6] = {56, 48, 40, 32, 8, 0};
    for (int r = 0; r < 6; ++r) {
        int shift = shifts[r];
        if (tid < 256) hist[tid] = 0;
        __syncthreads();
        u64 P = s_P, M = s_M;
        for (int i = tid; i < NANCH; i += 1024) {
            u64 key = KB[i];
            if ((key & M) == P)
                atomicAdd(&hist[(u32)(key >> shift) & 0xFFu], 1u);
        }
        __syncthreads();
        // inclusive scan of hist into hsc (Hillis-Steele over 256)
        if (tid < 256) hsc[tid] = hist[tid];
        __syncthreads();
        for (int d = 1; d < 256; d <<= 1) {
            u32 add = 0;
            if (tid < 256 && tid >= d) add = hsc[tid - d];
            __syncthreads();
            if (tid < 256) hsc[tid] += add;
            __syncthreads();
        }
        // find digit bucket containing current rank
        if (tid < 256) {
            u32 rank = s_rank;
            u32 inc = hsc[tid];
            u32 cb = inc - hist[tid];
            if (cb < rank && rank <= inc) {
                s_rank = rank - cb;
                s_P = s_P | ((u64)tid << shift);
                s_M = s_M | (0xFFull << shift);
            }
        }
        __syncthreads();
    }
    u64 T = s_P;   // the 2048th-smallest key (keys are unique)

    // ---- Phase B: compact the 2048 keys <= T into LDS ----
    for (int i = tid; i < NANCH; i += 1024) {
        u64 key = KB[i];
        if (key <= T) {
            u32 pos = atomicAdd(&s_cnt, 1u);
            sk[pos] = key;
        }
    }
    __syncthreads();

    // ---- Phase C: bitonic sort 2048 keys ascending ----
    for (int k = 2; k <= NSEL; k <<= 1) {
        for (int j = k >> 1; j > 0; j >>= 1) {
            int n = tid;   // exactly NSEL/2 = 1024 compare-exchanges
            int i = ((n & ~(j - 1)) << 1) | (n & (j - 1));
            int l = i | j;
            u64 a = sk[i], c = sk[l];
            bool up = ((i & k) == 0);
            if ((a > c) == up) { sk[i] = c; sk[l] = a; }
            __syncthreads();
        }
    }

    // ---- Phase D: gather selected entries ----
    for (int r = tid; r < NSEL; r += 1024) {
        u64 key = sk[r];
        int a = (int)(key & 0xFFFFFFFFu);
        size_t src = (size_t)b * NANCH + a;
        float4 bx = boxes[src];
        int c = cls[src];
        float sc = score[src];
        float off = (float)c * MAXWH;
        float4 sb;
        sb.x = bx.x + off; sb.y = bx.y + off;
        sb.z = bx.z + off; sb.w = bx.w + off;
        float area = (sb.z - sb.x) * (sb.w - sb.y);
        size_t o = (size_t)b * NSEL + r;
        sel_box[o] = bx; sel_sbox[o] = sb; sel_area[o] = area;
        sel_score[o] = sc; sel_cls[o] = c;
    }
}

// ---------------- Kernel 3: IoU predicate bitmask rows ----------------
__global__ __launch_bounds__(256) void k_iou(const float4* __restrict__ sel_sbox,
                                             const float* __restrict__ sel_area,
                                             u64* __restrict__ rowmask) {
    int b = blockIdx.y;
    int i = blockIdx.x;
    const float4* SB = sel_sbox + (size_t)b * NSEL;
    const float* AR = sel_area + (size_t)b * NSEL;
    float4 bi = SB[i];
    float ai = AR[i];
    int lane = threadIdx.x & 63;
    int wv = threadIdx.x >> 6;
    #pragma unroll
    for (int kk = 0; kk < 8; ++kk) {
        int chunk = wv * 8 + kk;
        int j = chunk * 64 + lane;
        float4 bj = SB[j];
        float aj = AR[j];
        float ltx = fmaxf(bi.x, bj.x), lty = fmaxf(bi.y, bj.y);
        float rbx = fminf(bi.z, bj.z), rby = fminf(bi.w, bj.w);
        float w = fmaxf(rbx - ltx, 0.0f), h = fmaxf(rby - lty, 0.0f);
        float inter = w * h;
        float iou = inter / (ai + aj - inter + 1e-16f);
        u64 m = __ballot(iou > NMS_T);
        if (lane == 0) rowmask[((size_t)b * NSEL + i) * NWORD + chunk] = m;
    }
}

// ---------------- Kernel 4: chunked NMS scan + output ----------------
__global__ __launch_bounds__(64) void k_nms(const u64* __restrict__ rowmask,
                                            const float4* __restrict__ sel_box,
                                            const float* __restrict__ sel_score,
                                            const int* __restrict__ sel_cls,
                                            float* __restrict__ out) {
    int b = blockIdx.x;
    int lane = threadIdx.x;
    const u64* RM = rowmask + (size_t)b * NSEL * NWORD;
    const float* SC = sel_score + (size_t)b * NSEL;

    // vreg: lane w holds valid word w (w < 32)
    u64 vreg = 0;
    for (int w = 0; w < NWORD; ++w) {
        bool p = SC[w * 64 + lane] >= 0.0f;
        u64 m = __ballot(p);
        if (lane == w) vreg = m;
    }

    u64 kreg = 0;   // lane c holds keep word of chunk c (c < 32)
    for (int d = 0; d < NWORD; ++d) {
        int row = d * 64 + lane;               // this lane's candidate in chunk d
        const u64* rp = RM + (size_t)row * NWORD;

        // cross-chunk suppression: any previously-kept j with iou > T?
        bool hit = false;
        #pragma unroll 8
        for (int c = 0; c < d; ++c) {
            u64 kc = __shfl(kreg, c);
            u64 rm = rp[c];
            hit = hit | ((rm & kc) != 0ULL);
        }
        u64 diag = rp[d];                      // intra-chunk suppressor bits
        u64 hitword = __ballot(hit);
        u64 vword = __shfl(vreg, d);
        u64 pend = vword & ~hitword;           // candidates still eligible

        // intra-chunk triangular resolution (all lanes compute identical k)
        u64 k = 0;
        #pragma unroll
        for (int t = 0; t < 64; ++t) {
            u64 rowt = __shfl(diag, t);        // independent of k -> pipelined
            bool kt = (((pend >> t) & 1ULL) != 0ULL) & ((rowt & k) == 0ULL);
            k |= ((u64)kt) << t;
        }
        if (lane == d) kreg = k;
    }

    // compact kept entries (already in descending-score order) into out
    int cnt = (lane < NWORD) ? __popcll(kreg) : 0;
    int pre = cnt;
    #pragma unroll
    for (int dd = 1; dd < 64; dd <<= 1) {
        int o = __shfl_up(pre, dd);
        if (lane >= dd) pre += o;
    }
    int total = __shfl(pre, 63);
    int base = pre - cnt;
    float* OUT = out + (size_t)b * MAXDET * 6;
    if (lane < NWORD) {
        u64 m = kreg;
        int r = 0;
        while (m) {
            int t = __ffsll((long long)m) - 1;
            m &= m - 1;
            int slot = base + r; ++r;
            if (slot < MAXDET) {
                int i = lane * 64 + t;
                size_t src = (size_t)b * NSEL + i;
                float4 bx = sel_box[src];
                float sc = SC[i];
                int c = sel_cls[src];
                float* o6 = OUT + slot * 6;
                o6[0] = bx.x; o6[1] = bx.y; o6[2] = bx.z; o6[3] = bx.w;
                o6[4] = sc; o6[5] = (float)c;
            }
        }
    }
    int start = total > MAXDET ? MAXDET : total;
    for (int s = start + lane; s < MAXDET; s += 64) {
        float* o6 = OUT + s * 6;
        o6[0] = 0.0f; o6[1] = 0.0f; o6[2] = 0.0f;
        o6[3] = 0.0f; o6[4] = 0.0f; o6[5] = 0.0f;
    }
}

// ---------------- Launcher ----------------
extern "C" void kernel_launch(void* const* d_in, const int* in_sizes, int n_in,
                              void* d_out, int out_size, void* d_ws, size_t ws_size,
                              hipStream_t stream) {
    const float* pred = (const float*)d_in[0];
    float* out = (float*)d_out;

    char* ws = (char*)d_ws;
    size_t off = 0;
    auto alloc = [&](size_t bytes) -> void* {
        void* p = ws + off;
        off += (bytes + 255) & ~(size_t)255;
        return p;
    };

    u64*    keys      = (u64*)   alloc((size_t)NBATCH * NSORT * 8);
    float4* boxes     = (float4*)alloc((size_t)NBATCH * NANCH * 16);
    int*    cls       = (int*)   alloc((size_t)NBATCH * NANCH * 4);
    float*  score     = (float*) alloc((size_t)NBATCH * NANCH * 4);
    float4* sel_box   = (float4*)alloc((size_t)NBATCH * NSEL * 16);
    float4* sel_sbox  = (float4*)alloc((size_t)NBATCH * NSEL * 16);
    float*  sel_area  = (float*) alloc((size_t)NBATCH * NSEL * 4);
    float*  sel_score = (float*) alloc((size_t)NBATCH * NSEL * 4);
    int*    sel_cls   = (int*)   alloc((size_t)NBATCH * NSEL * 4);
    u64*    rowmask   = (u64*)   alloc((size_t)NBATCH * NSEL * NWORD * 8);

    dim3 g1((NANCH + 127) / 128, NBATCH);
    k_prep<<<g1, 256, 0, stream>>>(pred, keys, boxes, cls, score);

    k_sel<<<NBATCH, 1024, 0, stream>>>(keys, boxes, cls, score,
                                       sel_box, sel_sbox, sel_area,
                                       sel_score, sel_cls);

    dim3 g3(NSEL, NBATCH);
    k_iou<<<g3, 256, 0, stream>>>(sel_sbox, sel_area, rowmask);

    k_nms<<<NBATCH, 64, 0, stream>>>(rowmask, sel_box, sel_score, sel_cls, out);
}

// Round 4
// 266.909 us; speedup vs baseline: 2.5331x; 1.0578x over previous
//
#include <hip/hip_runtime.h>
#include <hip/hip_bf16.h>
#include <stdint.h>

typedef unsigned long long u64;
typedef unsigned int u32;

#define NANCH 10647
#define NBATCH 16
#define NSORT 16384
#define NSEL 2048
#define NWORD 32
#define CONF_T 0.5f
#define NMS_T 0.5f
#define MAXDET 300
#define MAXWH 4096.0f

// ---------------- Kernel 1: per-anchor prep ----------------
__global__ __launch_bounds__(256) void k_prep(const float* __restrict__ pred,
                                              u64* __restrict__ keys,
                                              float4* __restrict__ boxes,
                                              int* __restrict__ cls,
                                              float* __restrict__ score) {
    __shared__ float sm[128 * 85];
    int b = blockIdx.y;
    int a0 = blockIdx.x * 128;
    int na = NANCH - a0; if (na > 128) na = 128;
    const float* src = pred + ((size_t)b * NANCH + a0) * 85;
    int tot = na * 85;
    for (int i = threadIdx.x; i < tot; i += 256) sm[i] = src[i];
    __syncthreads();
    int t = threadIdx.x;
    if (t < na) {
        const float* s = &sm[t * 85];
        float x = s[0], y = s[1], w = s[2], h = s[3], obj = s[4];
        float best = s[5] * obj; int arg = 0;
        #pragma unroll
        for (int c = 1; c < 80; ++c) {
            float v = s[5 + c] * obj;
            if (v > best) { best = v; arg = c; }
        }
        bool valid = obj >= CONF_T;
        float sc = valid ? best : -1.0f;
        int a = a0 + t;
        float4 bx;
        bx.x = x - w * 0.5f; bx.y = y - h * 0.5f;
        bx.z = x + w * 0.5f; bx.w = y + h * 0.5f;
        size_t o = (size_t)b * NANCH + a;
        boxes[o] = bx;
        cls[o] = arg;
        score[o] = sc;
        u32 u = __float_as_uint(sc);
        u32 v = (u & 0x80000000u) ? ~u : (u | 0x80000000u); // ascending map
        u32 hi = ~v;                                        // descending
        keys[(size_t)b * NSORT + a] = ((u64)hi << 32) | (u32)a;
    }
}

// ------- Kernel 2: radix-select top-2048 + bitonic sort + gather -------
__global__ __launch_bounds__(1024) void k_sel(const u64* __restrict__ keys,
                                              const float4* __restrict__ boxes,
                                              const int* __restrict__ cls,
                                              const float* __restrict__ score,
                                              float4* __restrict__ sel_box,
                                              float4* __restrict__ sel_sbox,
                                              float* __restrict__ sel_area,
                                              float* __restrict__ sel_score,
                                              int* __restrict__ sel_cls) {
    __shared__ u64 sk[NSEL];        // 16 KB
    __shared__ u32 hist[256];
    __shared__ u32 hsc[256];
    __shared__ u64 s_P;             // known-prefix value
    __shared__ u64 s_M;             // known-prefix mask
    __shared__ u32 s_rank;
    __shared__ u32 s_cnt;

    int b = blockIdx.x;
    int tid = threadIdx.x;
    const u64* KB = keys + (size_t)b * NSORT;

    if (tid == 0) { s_P = 0; s_M = 0; s_rank = NSEL; s_cnt = 0; }
    __syncthreads();

    // ---- Phase A: radix-select the 2048th-smallest key ----
    // key bits [31:14] are always zero (index < 16384), so 6 digit rounds
    const int shifts[6] = {56, 48, 40, 32, 8, 0};
    for (int r = 0; r < 6; ++r) {
        int shift = shifts[r];
        if (tid < 256) hist[tid] = 0;
        __syncthreads();
        u64 P = s_P, M = s_M;
        for (int i = tid; i < NANCH; i += 1024) {
            u64 key = KB[i];
            if ((key & M) == P)
                atomicAdd(&hist[(u32)(key >> shift) & 0xFFu], 1u);
        }
        __syncthreads();
        // inclusive scan of hist into hsc (Hillis-Steele over 256)
        if (tid < 256) hsc[tid] = hist[tid];
        __syncthreads();
        for (int d = 1; d < 256; d <<= 1) {
            u32 add = 0;
            if (tid < 256 && tid >= d) add = hsc[tid - d];
            __syncthreads();
            if (tid < 256) hsc[tid] += add;
            __syncthreads();
        }
        // find digit bucket containing current rank
        if (tid < 256) {
            u32 rank = s_rank;
            u32 inc = hsc[tid];
            u32 cb = inc - hist[tid];
            if (cb < rank && rank <= inc) {
                s_rank = rank - cb;
                s_P = s_P | ((u64)tid << shift);
                s_M = s_M | (0xFFull << shift);
            }
        }
        __syncthreads();
    }
    u64 T = s_P;   // the 2048th-smallest key (keys are unique)

    // ---- Phase B: compact the 2048 keys <= T into LDS ----
    for (int i = tid; i < NANCH; i += 1024) {
        u64 key = KB[i];
        if (key <= T) {
            u32 pos = atomicAdd(&s_cnt, 1u);
            sk[pos] = key;
        }
    }
    __syncthreads();

    // ---- Phase C: bitonic sort 2048 keys ascending ----
    for (int k = 2; k <= NSEL; k <<= 1) {
        for (int j = k >> 1; j > 0; j >>= 1) {
            int n = tid;   // exactly NSEL/2 = 1024 compare-exchanges
            int i = ((n & ~(j - 1)) << 1) | (n & (j - 1));
            int l = i | j;
            u64 a = sk[i], c = sk[l];
            bool up = ((i & k) == 0);
            if ((a > c) == up) { sk[i] = c; sk[l] = a; }
            __syncthreads();
        }
    }

    // ---- Phase D: gather selected entries ----
    for (int r = tid; r < NSEL; r += 1024) {
        u64 key = sk[r];
        int a = (int)(key & 0xFFFFFFFFu);
        size_t src = (size_t)b * NANCH + a;
        float4 bx = boxes[src];
        int c = cls[src];
        float sc = score[src];
        float off = (float)c * MAXWH;
        float4 sb;
        sb.x = bx.x + off; sb.y = bx.y + off;
        sb.z = bx.z + off; sb.w = bx.w + off;
        float area = (sb.z - sb.x) * (sb.w - sb.y);
        size_t o = (size_t)b * NSEL + r;
        sel_box[o] = bx; sel_sbox[o] = sb; sel_area[o] = area;
        sel_score[o] = sc; sel_cls[o] = c;
    }
}

// ---------------- Kernel 3: IoU predicate bitmask rows ----------------
__global__ __launch_bounds__(256) void k_iou(const float4* __restrict__ sel_sbox,
                                             const float* __restrict__ sel_area,
                                             u64* __restrict__ rowmask) {
    int b = blockIdx.y;
    int i = blockIdx.x;
    const float4* SB = sel_sbox + (size_t)b * NSEL;
    const float* AR = sel_area + (size_t)b * NSEL;
    float4 bi = SB[i];
    float ai = AR[i];
    int lane = threadIdx.x & 63;
    int wv = threadIdx.x >> 6;
    #pragma unroll
    for (int kk = 0; kk < 8; ++kk) {
        int chunk = wv * 8 + kk;
        int j = chunk * 64 + lane;
        float4 bj = SB[j];
        float aj = AR[j];
        float ltx = fmaxf(bi.x, bj.x), lty = fmaxf(bi.y, bj.y);
        float rbx = fminf(bi.z, bj.z), rby = fminf(bi.w, bj.w);
        float w = fmaxf(rbx - ltx, 0.0f), h = fmaxf(rby - lty, 0.0f);
        float inter = w * h;
        float iou = inter / (ai + aj - inter + 1e-16f);
        u64 m = __ballot(iou > NMS_T);
        if (lane == 0) rowmask[((size_t)b * NSEL + i) * NWORD + chunk] = m;
    }
}

// ------- Kernel 4: chunked NMS scan (LDS broadcast, no shfl) + output -------
__global__ __launch_bounds__(64) void k_nms(const u64* __restrict__ rowmask,
                                            const float4* __restrict__ sel_box,
                                            const float* __restrict__ sel_score,
                                            const int* __restrict__ sel_cls,
                                            float* __restrict__ out) {
    __shared__ u64 skeep[NWORD];
    __shared__ u64 svalid[NWORD];
    __shared__ u64 sdiag[64];
    int b = blockIdx.x;
    int lane = threadIdx.x;
    const u64* RM = rowmask + (size_t)b * NSEL * NWORD;
    const float* SC = sel_score + (size_t)b * NSEL;

    // valid words into LDS
    for (int w = 0; w < NWORD; ++w) {
        bool p = SC[w * 64 + lane] >= 0.0f;
        u64 m = __ballot(p);
        if (lane == 0) svalid[w] = m;
    }
    if (lane < NWORD) skeep[lane] = 0ULL;
    __syncthreads();

    u64 kreg = 0;   // lane d will hold keep word of chunk d (d < 32)
    for (int d = 0; d < NWORD; ++d) {
        int row = d * 64 + lane;               // this lane's candidate in chunk d
        const u64* rp = RM + (size_t)row * NWORD;

        // cross-chunk suppression via LDS-broadcast keep words
        bool hit = false;
        #pragma unroll 4
        for (int c = 0; c < d; ++c) {
            hit = hit | ((rp[c] & skeep[c]) != 0ULL);
        }
        u64 diag = rp[d];                      // intra-chunk suppressor bits
        u64 hitword = __ballot(hit);
        u64 pend = svalid[d] & ~hitword;       // candidates still eligible
        sdiag[lane] = diag;
        __syncthreads();

        // intra-chunk triangular resolution (all lanes compute identical k)
        u64 k = 0;
        #pragma unroll 8
        for (int t = 0; t < 64; ++t) {
            u64 rowt = sdiag[t];               // LDS broadcast, k-independent
            bool kt = (((pend >> t) & 1ULL) != 0ULL) & ((rowt & k) == 0ULL);
            k |= ((u64)kt) << t;
        }
        if (lane == 0) skeep[d] = k;
        if (lane == d) kreg = k;
        __syncthreads();
    }

    // compact kept entries (already in descending-score order) into out
    int cnt = (lane < NWORD) ? __popcll(kreg) : 0;
    int pre = cnt;
    #pragma unroll
    for (int dd = 1; dd < 64; dd <<= 1) {
        int o = __shfl_up(pre, dd);
        if (lane >= dd) pre += o;
    }
    int total = __shfl(pre, 63);
    int base = pre - cnt;
    float* OUT = out + (size_t)b * MAXDET * 6;
    if (lane < NWORD) {
        u64 m = kreg;
        int r = 0;
        while (m) {
            int t = __ffsll((long long)m) - 1;
            m &= m - 1;
            int slot = base + r; ++r;
            if (slot < MAXDET) {
                int i = lane * 64 + t;
                size_t src = (size_t)b * NSEL + i;
                float4 bx = sel_box[src];
                float sc = SC[i];
                int c = sel_cls[src];
                float* o6 = OUT + slot * 6;
                o6[0] = bx.x; o6[1] = bx.y; o6[2] = bx.z; o6[3] = bx.w;
                o6[4] = sc; o6[5] = (float)c;
            }
        }
    }
    int start = total > MAXDET ? MAXDET : total;
    for (int s = start + lane; s < MAXDET; s += 64) {
        float* o6 = OUT + s * 6;
        o6[0] = 0.0f; o6[1] = 0.0f; o6[2] = 0.0f;
        o6[3] = 0.0f; o6[4] = 0.0f; o6[5] = 0.0f;
    }
}

// ---------------- Launcher ----------------
extern "C" void kernel_launch(void* const* d_in, const int* in_sizes, int n_in,
                              void* d_out, int out_size, void* d_ws, size_t ws_size,
                              hipStream_t stream) {
    const float* pred = (const float*)d_in[0];
    float* out = (float*)d_out;

    char* ws = (char*)d_ws;
    size_t off = 0;
    auto alloc = [&](size_t bytes) -> void* {
        void* p = ws + off;
        off += (bytes + 255) & ~(size_t)255;
        return p;
    };

    u64*    keys      = (u64*)   alloc((size_t)NBATCH * NSORT * 8);
    float4* boxes     = (float4*)alloc((size_t)NBATCH * NANCH * 16);
    int*    cls       = (int*)   alloc((size_t)NBATCH * NANCH * 4);
    float*  score     = (float*) alloc((size_t)NBATCH * NANCH * 4);
    float4* sel_box   = (float4*)alloc((size_t)NBATCH * NSEL * 16);
    float4* sel_sbox  = (float4*)alloc((size_t)NBATCH * NSEL * 16);
    float*  sel_area  = (float*) alloc((size_t)NBATCH * NSEL * 4);
    float*  sel_score = (float*) alloc((size_t)NBATCH * NSEL * 4);
    int*    sel_cls   = (int*)   alloc((size_t)NBATCH * NSEL * 4);
    u64*    rowmask   = (u64*)   alloc((size_t)NBATCH * NSEL * NWORD * 8);

    dim3 g1((NANCH + 127) / 128, NBATCH);
    k_prep<<<g1, 256, 0, stream>>>(pred, keys, boxes, cls, score);

    k_sel<<<NBATCH, 1024, 0, stream>>>(keys, boxes, cls, score,
                                       sel_box, sel_sbox, sel_area,
                                       sel_score, sel_cls);

    dim3 g3(NSEL, NBATCH);
    k_iou<<<g3, 256, 0, stream>>>(sel_sbox, sel_area, rowmask);

    k_nms<<<NBATCH, 64, 0, stream>>>(rowmask, sel_box, sel_score, sel_cls, out);
}

// Round 5
// 235.250 us; speedup vs baseline: 2.8740x; 1.1346x over previous
//
#include <hip/hip_runtime.h>
#include <hip/hip_bf16.h>
#include <stdint.h>

typedef unsigned long long u64;
typedef unsigned int u32;

#define NANCH 10647
#define NBATCH 16
#define NSORT 16384
#define NSEL 2048
#define NWORD 32
#define CONF_T 0.5f
#define NMS_T 0.5f
#define MAXDET 300
#define MAXWH 4096.0f

// ---------------- Kernel 1: per-anchor prep ----------------
__global__ __launch_bounds__(256) void k_prep(const float* __restrict__ pred,
                                              u64* __restrict__ keys,
                                              float4* __restrict__ boxes,
                                              int* __restrict__ cls,
                                              float* __restrict__ score) {
    __shared__ float sm[128 * 85];
    int b = blockIdx.y;
    int a0 = blockIdx.x * 128;
    int na = NANCH - a0; if (na > 128) na = 128;
    const float* src = pred + ((size_t)b * NANCH + a0) * 85;
    int tot = na * 85;
    for (int i = threadIdx.x; i < tot; i += 256) sm[i] = src[i];
    __syncthreads();
    int t = threadIdx.x;
    if (t < na) {
        const float* s = &sm[t * 85];
        float x = s[0], y = s[1], w = s[2], h = s[3], obj = s[4];
        float best = s[5] * obj; int arg = 0;
        #pragma unroll
        for (int c = 1; c < 80; ++c) {
            float v = s[5 + c] * obj;
            if (v > best) { best = v; arg = c; }
        }
        bool valid = obj >= CONF_T;
        float sc = valid ? best : -1.0f;
        int a = a0 + t;
        float4 bx;
        bx.x = x - w * 0.5f; bx.y = y - h * 0.5f;
        bx.z = x + w * 0.5f; bx.w = y + h * 0.5f;
        size_t o = (size_t)b * NANCH + a;
        boxes[o] = bx;
        cls[o] = arg;
        score[o] = sc;
        u32 u = __float_as_uint(sc);
        u32 v = (u & 0x80000000u) ? ~u : (u | 0x80000000u); // ascending map
        u32 hi = ~v;                                        // descending
        keys[(size_t)b * NSORT + a] = ((u64)hi << 32) | (u32)a;
    }
}

// ------- Kernel 2: radix-select top-2048 + bitonic sort + gather -------
__global__ __launch_bounds__(1024) void k_sel(const u64* __restrict__ keys,
                                              const float4* __restrict__ boxes,
                                              const int* __restrict__ cls,
                                              const float* __restrict__ score,
                                              float4* __restrict__ sel_box,
                                              float4* __restrict__ sel_sbox,
                                              float* __restrict__ sel_area,
                                              float* __restrict__ sel_score,
                                              int* __restrict__ sel_cls) {
    __shared__ u64 sk[NSEL];        // 16 KB
    __shared__ u32 hist[256];
    __shared__ u32 hsc[256];
    __shared__ u64 s_P;             // known-prefix value
    __shared__ u64 s_M;             // known-prefix mask
    __shared__ u32 s_rank;
    __shared__ u32 s_cnt;

    int b = blockIdx.x;
    int tid = threadIdx.x;
    const u64* KB = keys + (size_t)b * NSORT;

    if (tid == 0) { s_P = 0; s_M = 0; s_rank = NSEL; s_cnt = 0; }
    __syncthreads();

    // ---- Phase A: radix-select the 2048th-smallest key ----
    // key bits [31:14] are always zero (index < 16384), so 6 digit rounds
    const int shifts[6] = {56, 48, 40, 32, 8, 0};
    for (int r = 0; r < 6; ++r) {
        int shift = shifts[r];
        if (tid < 256) hist[tid] = 0;
        __syncthreads();
        u64 P = s_P, M = s_M;
        for (int i = tid; i < NANCH; i += 1024) {
            u64 key = KB[i];
            if ((key & M) == P)
                atomicAdd(&hist[(u32)(key >> shift) & 0xFFu], 1u);
        }
        __syncthreads();
        // inclusive scan of hist into hsc (Hillis-Steele over 256)
        if (tid < 256) hsc[tid] = hist[tid];
        __syncthreads();
        for (int d = 1; d < 256; d <<= 1) {
            u32 add = 0;
            if (tid < 256 && tid >= d) add = hsc[tid - d];
            __syncthreads();
            if (tid < 256) hsc[tid] += add;
            __syncthreads();
        }
        // find digit bucket containing current rank
        if (tid < 256) {
            u32 rank = s_rank;
            u32 inc = hsc[tid];
            u32 cb = inc - hist[tid];
            if (cb < rank && rank <= inc) {
                s_rank = rank - cb;
                s_P = s_P | ((u64)tid << shift);
                s_M = s_M | (0xFFull << shift);
            }
        }
        __syncthreads();
    }
    u64 T = s_P;   // the 2048th-smallest key (keys are unique)

    // ---- Phase B: compact the 2048 keys <= T into LDS ----
    for (int i = tid; i < NANCH; i += 1024) {
        u64 key = KB[i];
        if (key <= T) {
            u32 pos = atomicAdd(&s_cnt, 1u);
            sk[pos] = key;
        }
    }
    __syncthreads();

    // ---- Phase C: bitonic sort 2048 keys ascending ----
    for (int k = 2; k <= NSEL; k <<= 1) {
        for (int j = k >> 1; j > 0; j >>= 1) {
            int n = tid;   // exactly NSEL/2 = 1024 compare-exchanges
            int i = ((n & ~(j - 1)) << 1) | (n & (j - 1));
            int l = i | j;
            u64 a = sk[i], c = sk[l];
            bool up = ((i & k) == 0);
            if ((a > c) == up) { sk[i] = c; sk[l] = a; }
            __syncthreads();
        }
    }

    // ---- Phase D: gather selected entries ----
    for (int r = tid; r < NSEL; r += 1024) {
        u64 key = sk[r];
        int a = (int)(key & 0xFFFFFFFFu);
        size_t src = (size_t)b * NANCH + a;
        float4 bx = boxes[src];
        int c = cls[src];
        float sc = score[src];
        float off = (float)c * MAXWH;
        float4 sb;
        sb.x = bx.x + off; sb.y = bx.y + off;
        sb.z = bx.z + off; sb.w = bx.w + off;
        float area = (sb.z - sb.x) * (sb.w - sb.y);
        size_t o = (size_t)b * NSEL + r;
        sel_box[o] = bx; sel_sbox[o] = sb; sel_area[o] = area;
        sel_score[o] = sc; sel_cls[o] = c;
    }
}

// ---------------- Kernel 3: IoU predicate bitmask rows ----------------
__global__ __launch_bounds__(256) void k_iou(const float4* __restrict__ sel_sbox,
                                             const float* __restrict__ sel_area,
                                             u64* __restrict__ rowmask) {
    int b = blockIdx.y;
    int i = blockIdx.x;
    const float4* SB = sel_sbox + (size_t)b * NSEL;
    const float* AR = sel_area + (size_t)b * NSEL;
    float4 bi = SB[i];
    float ai = AR[i];
    int lane = threadIdx.x & 63;
    int wv = threadIdx.x >> 6;
    #pragma unroll
    for (int kk = 0; kk < 8; ++kk) {
        int chunk = wv * 8 + kk;
        int j = chunk * 64 + lane;
        float4 bj = SB[j];
        float aj = AR[j];
        float ltx = fmaxf(bi.x, bj.x), lty = fmaxf(bi.y, bj.y);
        float rbx = fminf(bi.z, bj.z), rby = fminf(bi.w, bj.w);
        float w = fmaxf(rbx - ltx, 0.0f), h = fmaxf(rby - lty, 0.0f);
        float inter = w * h;
        float iou = inter / (ai + aj - inter + 1e-16f);
        u64 m = __ballot(iou > NMS_T);
        if (lane == 0) rowmask[((size_t)b * NSEL + i) * NWORD + chunk] = m;
    }
}

// ------- Kernel 4: incremental NMS, 8 waves, double-buffered LDS -------
__global__ __launch_bounds__(512) void k_nms(const u64* __restrict__ rowmask,
                                             const float4* __restrict__ sel_box,
                                             const float* __restrict__ sel_score,
                                             const int* __restrict__ sel_cls,
                                             float* __restrict__ out) {
    __shared__ u64 sblk[2][32][65];   // [buf][word][row], padded (33.3 KB)
    __shared__ u64 ssup[NWORD];       // suppressed-candidate bit vector
    __shared__ u64 svalid[NWORD];
    __shared__ u64 skeep[NWORD];
    __shared__ u32 s_total;

    int b = blockIdx.x;
    int tid = threadIdx.x;
    int lane = tid & 63;
    int wv = tid >> 6;
    const u64* RM = rowmask + (size_t)b * NSEL * NWORD;
    const float* SC = sel_score + (size_t)b * NSEL;

    if (tid < NWORD) { ssup[tid] = 0ULL; skeep[tid] = 0ULL; }
    // valid words: wave wv handles words wv, wv+8, wv+16, wv+24
    for (int w = wv; w < NWORD; w += 8) {
        bool p = SC[w * 64 + lane] >= 0.0f;
        u64 m = __ballot(p);
        if (lane == 0) svalid[w] = m;
    }
    // preload chunk 0 block (16 KB contiguous), transposed into LDS
    {
        const u64* src = RM + (size_t)tid * 4;
        ulonglong2 a = *(const ulonglong2*)(src);
        ulonglong2 c = *(const ulonglong2*)(src + 2);
        int r = tid >> 3, w0 = (tid & 7) * 4;
        sblk[0][w0 + 0][r] = a.x; sblk[0][w0 + 1][r] = a.y;
        sblk[0][w0 + 2][r] = c.x; sblk[0][w0 + 3][r] = c.y;
    }
    __syncthreads();

    for (int d = 0; d < NWORD; ++d) {
        int cur = d & 1;
        // issue prefetch loads for chunk d+1 (coalesced; land during resolve)
        ulonglong2 pa, pc;
        int r = tid >> 3, w0 = (tid & 7) * 4;
        bool pf = (d + 1 < NWORD);
        if (pf) {
            const u64* src = RM + (size_t)(d + 1) * 2048 + (size_t)tid * 4;
            pa = *(const ulonglong2*)(src);
            pc = *(const ulonglong2*)(src + 2);
        }
        // wave 0: resolve chunk d (serial greedy within chunk)
        if (wv == 0) {
            u64 pend = svalid[d] & ~ssup[d];
            u64 k = 0;
            #pragma unroll 8
            for (int t = 0; t < 64; ++t) {
                u64 rowt = sblk[cur][d][t];    // LDS broadcast
                bool kt = (((pend >> t) & 1ULL) != 0ULL) & ((rowt & k) == 0ULL);
                k |= ((u64)kt) << t;
            }
            if (lane == 0) skeep[d] = k;
        }
        // write prefetched block into the other buffer
        if (pf) {
            sblk[cur ^ 1][w0 + 0][r] = pa.x; sblk[cur ^ 1][w0 + 1][r] = pa.y;
            sblk[cur ^ 1][w0 + 2][r] = pc.x; sblk[cur ^ 1][w0 + 3][r] = pc.y;
        }
        __syncthreads();
        // OR phase: fold kept rows of chunk d into ssup (symmetry: row==col)
        {
            u64 k = skeep[d];
            int w = tid & 31, g = tid >> 5;    // 16 groups x 32 words
            u64 acc = 0;
            #pragma unroll
            for (int t = g; t < 64; t += 16)
                if ((k >> t) & 1ULL) acc |= sblk[cur][w][t];
            if (acc) atomicOr(&ssup[w], acc);
        }
        __syncthreads();
    }

    // ---- epilogue: compact kept entries (descending-score order) ----
    if (wv == 0) {
        u64 kreg = (lane < NWORD) ? skeep[lane] : 0ULL;
        int cnt = __popcll(kreg);
        int pre = cnt;
        #pragma unroll
        for (int dd = 1; dd < 64; dd <<= 1) {
            int o = __shfl_up(pre, dd);
            if (lane >= dd) pre += o;
        }
        int total = __shfl(pre, 63);
        int base = pre - cnt;
        float* OUT = out + (size_t)b * MAXDET * 6;
        if (lane < NWORD) {
            u64 m = kreg;
            int rr = 0;
            while (m) {
                int t = __ffsll((long long)m) - 1;
                m &= m - 1;
                int slot = base + rr; ++rr;
                if (slot < MAXDET) {
                    int i = lane * 64 + t;
                    size_t src = (size_t)b * NSEL + i;
                    float4 bx = sel_box[src];
                    float sc = SC[i];
                    int c = sel_cls[src];
                    float* o6 = OUT + slot * 6;
                    o6[0] = bx.x; o6[1] = bx.y; o6[2] = bx.z; o6[3] = bx.w;
                    o6[4] = sc; o6[5] = (float)c;
                }
            }
        }
        if (lane == 0) s_total = (total > MAXDET) ? MAXDET : total;
    }
    __syncthreads();
    int start = (int)s_total;
    float* OUT = out + (size_t)b * MAXDET * 6;
    for (int s = start + tid; s < MAXDET; s += 512) {
        float* o6 = OUT + s * 6;
        o6[0] = 0.0f; o6[1] = 0.0f; o6[2] = 0.0f;
        o6[3] = 0.0f; o6[4] = 0.0f; o6[5] = 0.0f;
    }
}

// ---------------- Launcher ----------------
extern "C" void kernel_launch(void* const* d_in, const int* in_sizes, int n_in,
                              void* d_out, int out_size, void* d_ws, size_t ws_size,
                              hipStream_t stream) {
    const float* pred = (const float*)d_in[0];
    float* out = (float*)d_out;

    char* ws = (char*)d_ws;
    size_t off = 0;
    auto alloc = [&](size_t bytes) -> void* {
        void* p = ws + off;
        off += (bytes + 255) & ~(size_t)255;
        return p;
    };

    u64*    keys      = (u64*)   alloc((size_t)NBATCH * NSORT * 8);
    float4* boxes     = (float4*)alloc((size_t)NBATCH * NANCH * 16);
    int*    cls       = (int*)   alloc((size_t)NBATCH * NANCH * 4);
    float*  score     = (float*) alloc((size_t)NBATCH * NANCH * 4);
    float4* sel_box   = (float4*)alloc((size_t)NBATCH * NSEL * 16);
    float4* sel_sbox  = (float4*)alloc((size_t)NBATCH * NSEL * 16);
    float*  sel_area  = (float*) alloc((size_t)NBATCH * NSEL * 4);
    float*  sel_score = (float*) alloc((size_t)NBATCH * NSEL * 4);
    int*    sel_cls   = (int*)   alloc((size_t)NBATCH * NSEL * 4);
    u64*    rowmask   = (u64*)   alloc((size_t)NBATCH * NSEL * NWORD * 8);

    dim3 g1((NANCH + 127) / 128, NBATCH);
    k_prep<<<g1, 256, 0, stream>>>(pred, keys, boxes, cls, score);

    k_sel<<<NBATCH, 1024, 0, stream>>>(keys, boxes, cls, score,
                                       sel_box, sel_sbox, sel_area,
                                       sel_score, sel_cls);

    dim3 g3(NSEL, NBATCH);
    k_iou<<<g3, 256, 0, stream>>>(sel_sbox, sel_area, rowmask);

    k_nms<<<NBATCH, 512, 0, stream>>>(rowmask, sel_box, sel_score, sel_cls, out);
}